// Round 3
// baseline (273.938 us; speedup 1.0000x reference)
//
#include <hip/hip_runtime.h>
#include <hip/hip_bf16.h>

#define NN   12288
#define EE   393216
#define WELL 128                // ELL slots per row (pow2; max degree ~64)
#define NELL (NN*WELL)
#define BG   16
#define FIN  15
#define FH1  32
#define FH2  64
#define NCL  11
#define BNEPS 1e-5f
#define NBANK 32

typedef unsigned long long u64;
static inline int cdiv(long a, long b){ return (int)((a + b - 1) / b); }

__device__ __forceinline__ int getIdx(const void* p, long i, int is64){
  return is64 ? (int)((const long long*)p)[i] : ((const int*)p)[i];
}

// ---- pre: zero deg_cnt + csp banks + embf; detect int width ----
__global__ void k_pre(u64* deg_cnt, float* csp1, float* csp2, float* csp3,
                      float* embf, const void* ei, const void* batch, int* flags){
  int g = blockIdx.x*256 + threadIdx.x;
  if (g < NN) deg_cnt[g] = 0ull;
  if (g < NBANK*128){ csp1[g] = 0.f; csp2[g] = 0.f; csp3[g] = 0.f; }
  if (g < BG*64) embf[g] = 0.f;          // pool accumulates via atomicMax, vals >= 0
  if (blockIdx.x == 0 && threadIdx.x < 64){
    const int* a = (const int*)ei;
    unsigned long long m0 = __ballot(a[2*threadIdx.x + 1] == 0);
    const int* b = (const int*)batch;
    int j = 96*threadIdx.x;
    unsigned long long m1 = __ballot(b[2*j + 1] == 0);
    if (threadIdx.x == 0){
      flags[0] = (m0 == ~0ull) ? 1 : 0;
      flags[1] = (m1 == ~0ull) ? 1 : 0;
    }
  }
}

// ---- edge pass: ONE u64 atomic per edge; returned count = ELL slot ----
__global__ void k_edge(const float* ea, const float* we, const float* bedg,
                       const void* ei, const int* flags, u64* deg_cnt, u64* csr_p){
  int e = blockIdx.x*256 + threadIdx.x;
  if (e >= EE) return;
  int is64 = flags[0];
  float2 eav = ((const float2*)ea)[e];
  float z = eav.x*we[0] + eav.y*we[1] + bedg[0];
  float w = 1.0f/(1.0f + expf(-z));
  int r = getIdx(ei, e, is64);
  int c = getIdx(ei, (long)EE + e, is64);
  u64 add = (1ull << 32) | (u64)__float2uint_rn(w * 1048576.0f);
  u64 old = atomicAdd(&deg_cnt[r], add);
  int slot = (int)(old >> 32);
  if (slot < WELL)
    csr_p[((long)r << 7) + slot] = (u64)(unsigned)c | ((u64)__float_as_uint(w) << 32);
}

// ---- dis LUT: rsqrt(deg) per node (replaces the 1.57M-thread k_fix sweep) ----
__global__ void k_dis(const u64* __restrict__ deg_cnt, float* __restrict__ dis){
  int g = blockIdx.x*256 + threadIdx.x;
  if (g < NN){
    unsigned lo = (unsigned)(deg_cnt[g] & 0xffffffffull);
    dis[g] = rsqrtf(1.0f + (float)lo * (1.0f/1048576.0f));
  }
}

// ---- fused GCN layer, one tile per block, ELL chunks of 8 + prefetch.
// Column normalization via dis[] LUT (k_fix eliminated).
// BN coefficients computed per-block from csp banks (k_stat eliminated).
template<int F, int FP, int FO, int APPLY_BN>
__global__ void __launch_bounds__(256) k_layer(
    const float* __restrict__ Hin,
    const float* __restrict__ cspin, const float* __restrict__ gam,
    const float* __restrict__ bet,
    const float* __restrict__ W, const float* __restrict__ bias,
    const u64* __restrict__ deg_cnt, const u64* __restrict__ csr_p,
    const float* __restrict__ dis,
    float* __restrict__ Pout, float* __restrict__ csout){
  const int R = 256/FP;
  __shared__ float At[R][FP];
  __shared__ float lcs[FO], lcq[FO];
  __shared__ float lsc[64], lsh[64];
  if (threadIdx.x < FO){ lcs[threadIdx.x] = 0.f; lcq[threadIdx.x] = 0.f; }
  if (APPLY_BN && threadIdx.x < F){
    float s = 0.f, q = 0.f;
    #pragma unroll
    for (int b = 0; b < NBANK; b++){
      s += cspin[b*128 + threadIdx.x];
      q += cspin[b*128 + 64 + threadIdx.x];
    }
    float mu  = s*(1.0f/NN);
    float var = q*(1.0f/NN) - mu*mu;
    float sc = gam[threadIdx.x]*rsqrtf(var + BNEPS);
    lsc[threadIdx.x] = sc;
    lsh[threadIdx.x] = bet[threadIdx.x] - mu*sc;
  }
  __syncthreads();
  int f = threadIdx.x % FP, lr = threadIdx.x / FP;
  float sc = 1.f, sh = 0.f;
  if (APPLY_BN && f < F){ sc = lsc[f]; sh = lsh[f]; }
  int row = blockIdx.x*R + lr;
  if (f < F){
    float d = dis[row];
    int n = (int)(deg_cnt[row] >> 32);
    n = n < WELL ? n : WELL;
    float v0 = Hin[row*F + f];
    if (APPLY_BN) v0 = fmaxf(v0*sc + sh, 0.f);
    float acc = d * v0;                       // self loop
    int nch = (n + 7) >> 3;
    const uint4* pb = (const uint4*)(csr_p + ((long)row << 7));
    if (nch > 0){
      uint4 a0 = pb[0], a1 = pb[1], a2 = pb[2], a3 = pb[3];
      for (int ch = 0; ch < nch; ch++){
        uint4 b0, b1, b2, b3;
        bool more = (ch + 1 < nch);
        if (more){ b0 = pb[4*ch+4]; b1 = pb[4*ch+5]; b2 = pb[4*ch+6]; b3 = pb[4*ch+7]; }
        int base = ch*8;
        if (base + 8 > n){                    // mask garbage tail slots
          if (base+0 >= n){ a0.x = 0u; a0.y = 0u; }
          if (base+1 >= n){ a0.z = 0u; a0.w = 0u; }
          if (base+2 >= n){ a1.x = 0u; a1.y = 0u; }
          if (base+3 >= n){ a1.z = 0u; a1.w = 0u; }
          if (base+4 >= n){ a2.x = 0u; a2.y = 0u; }
          if (base+5 >= n){ a2.z = 0u; a2.w = 0u; }
          if (base+6 >= n){ a3.x = 0u; a3.y = 0u; }
          if (base+7 >= n){ a3.z = 0u; a3.w = 0u; }
        }
        float w0 = __uint_as_float(a0.y) * dis[(int)a0.x];
        float w1 = __uint_as_float(a0.w) * dis[(int)a0.z];
        float w2 = __uint_as_float(a1.y) * dis[(int)a1.x];
        float w3 = __uint_as_float(a1.w) * dis[(int)a1.z];
        float w4 = __uint_as_float(a2.y) * dis[(int)a2.x];
        float w5 = __uint_as_float(a2.w) * dis[(int)a2.z];
        float w6 = __uint_as_float(a3.y) * dis[(int)a3.x];
        float w7 = __uint_as_float(a3.w) * dis[(int)a3.z];
        float h0 = Hin[(int)a0.x*F + f];
        float h1 = Hin[(int)a0.z*F + f];
        float h2 = Hin[(int)a1.x*F + f];
        float h3 = Hin[(int)a1.z*F + f];
        float h4 = Hin[(int)a2.x*F + f];
        float h5 = Hin[(int)a2.z*F + f];
        float h6 = Hin[(int)a3.x*F + f];
        float h7 = Hin[(int)a3.z*F + f];
        if (APPLY_BN){
          h0 = fmaxf(h0*sc + sh, 0.f); h1 = fmaxf(h1*sc + sh, 0.f);
          h2 = fmaxf(h2*sc + sh, 0.f); h3 = fmaxf(h3*sc + sh, 0.f);
          h4 = fmaxf(h4*sc + sh, 0.f); h5 = fmaxf(h5*sc + sh, 0.f);
          h6 = fmaxf(h6*sc + sh, 0.f); h7 = fmaxf(h7*sc + sh, 0.f);
        }
        acc += w0*h0 + w1*h1 + w2*h2 + w3*h3
             + w4*h4 + w5*h5 + w6*h6 + w7*h7;
        if (more){ a0 = b0; a1 = b1; a2 = b2; a3 = b3; }
      }
    }
    At[lr][f] = d * acc;
  }
  __syncthreads();
  const int fo = threadIdx.x % FO;     // 256 % FO == 0
  float bb = bias[fo];
  for (int o = threadIdx.x; o < R*FO; o += 256){
    int l = o / FO;
    float s = bb;
    #pragma unroll
    for (int fi = 0; fi < F; fi++) s += At[l][fi] * W[fi*FO + fo];
    Pout[(blockIdx.x*R + l)*FO + fo] = s;
    atomicAdd(&lcs[fo], s);
    atomicAdd(&lcq[fo], s*s);
  }
  __syncthreads();
  if (threadIdx.x < FO){
    int bank = blockIdx.x & (NBANK-1);
    atomicAdd(&csout[bank*128 + threadIdx.x],      lcs[threadIdx.x]);
    atomicAdd(&csout[bank*128 + 64 + threadIdx.x], lcq[threadIdx.x]);
  }
}

// ---- pool: 16 chunks per graph (256 blocks); inline BN3 prep; atomicMax merge.
// Pooled values >= 0 (relu): int-compare on float bits is monotone; zero-init ok.
__global__ void k_pool(const float* P3, const float* csp, const float* gam,
                       const float* bet, const void* batch, const int* flags,
                       float* embf){
  __shared__ float lsc[64], lsh[64];
  if (threadIdx.x < 64){
    float s = 0.f, q = 0.f;
    #pragma unroll
    for (int b = 0; b < NBANK; b++){
      s += csp[b*128 + threadIdx.x];
      q += csp[b*128 + 64 + threadIdx.x];
    }
    float mu  = s*(1.0f/NN);
    float var = q*(1.0f/NN) - mu*mu;
    float sc = gam[threadIdx.x]*rsqrtf(var + BNEPS);
    lsc[threadIdx.x] = sc;
    lsh[threadIdx.x] = bet[threadIdx.x] - mu*sc;
  }
  __syncthreads();
  int is64 = flags[1];
  int b = blockIdx.x & 15, chunk = blockIdx.x >> 4;
  int lo = 0, hi = NN;
  while (lo < hi){ int m = (lo+hi)>>1; if (getIdx(batch, m, is64) < b) lo = m+1; else hi = m; }
  int start = lo;
  lo = start; hi = NN;
  while (lo < hi){ int m = (lo+hi)>>1; if (getIdx(batch, m, is64) < b+1) lo = m+1; else hi = m; }
  int end = lo;
  int f = threadIdx.x & 63, grp = threadIdx.x >> 6;
  float sc = lsc[f], sh = lsh[f];
  float m = 0.0f;
  for (int i = start + chunk*4 + grp; i < end; i += 64)
    m = fmaxf(m, P3[(long)i*FH2 + f]*sc + sh);
  __shared__ float shm[4][64];
  shm[grp][f] = m;
  __syncthreads();
  if (grp == 0){
    float v = fmaxf(fmaxf(shm[0][f], shm[1][f]), fmaxf(shm[2][f], shm[3][f]));
    atomicMax((int*)&embf[b*64 + f], __float_as_int(v));
  }
}

// ---- whole MLP head in ONE block (512 threads): fc1+BN+relu, fc2+BN+relu,
// fc3+log_softmax; also copies emb -> out. Replaces 3 dependent dispatches. ----
__global__ void __launch_bounds__(512) k_head(
    const float* __restrict__ embf,
    const float* __restrict__ wf1, const float* __restrict__ bf1,
    const float* __restrict__ gf1, const float* __restrict__ bef1,
    const float* __restrict__ wf2, const float* __restrict__ bf2,
    const float* __restrict__ gf2, const float* __restrict__ bef2,
    const float* __restrict__ wf3, const float* __restrict__ bf3,
    float* __restrict__ out){
  // 52 KB LDS: s1T[512][16] | zp[256][16] | sembT[64][16]; s2T aliases s1T,
  // sl aliases zp (each reuse separated by __syncthreads).
  __shared__ __align__(16) float smem[512*16 + 256*16 + 64*16];
  float* s1T   = smem;
  float* zp    = smem + 512*16;
  float* sembT = smem + 512*16 + 256*16;
  int t = threadIdx.x;
  for (int i = t; i < BG*64; i += 512){
    float v = embf[i];
    out[BG*NCL + i] = v;                     // emb copy to output
    sembT[(i & 63)*16 + (i >> 6)] = v;       // transposed [l][r]
  }
  __syncthreads();
  // fc1: one column c = t of 512
  float z[BG];
  #pragma unroll
  for (int r = 0; r < BG; r++) z[r] = 0.f;
  #pragma unroll 4
  for (int l = 0; l < 64; l++){
    float w = wf1[l*512 + t];
    const float4* e4 = (const float4*)&sembT[l*16];
    float4 e0 = e4[0], e1 = e4[1], e2 = e4[2], e3 = e4[3];
    z[0]  += e0.x*w; z[1]  += e0.y*w; z[2]  += e0.z*w; z[3]  += e0.w*w;
    z[4]  += e1.x*w; z[5]  += e1.y*w; z[6]  += e1.z*w; z[7]  += e1.w*w;
    z[8]  += e2.x*w; z[9]  += e2.y*w; z[10] += e2.z*w; z[11] += e2.w*w;
    z[12] += e3.x*w; z[13] += e3.y*w; z[14] += e3.z*w; z[15] += e3.w*w;
  }
  {
    float bb = bf1[t];
    float s = 0.f, q = 0.f;
    #pragma unroll
    for (int r = 0; r < BG; r++){ float zr = z[r] + bb; s += zr; q += zr*zr; }
    float mean = s*(1.0f/BG), var = q*(1.0f/BG) - mean*mean;
    float inv = rsqrtf(var + BNEPS);
    float gg = gf1[t], b2 = bef1[t];
    #pragma unroll
    for (int r = 0; r < BG; r++) z[r] = fmaxf(gg*(z[r] + bb - mean)*inv + b2, 0.f);
    float4* s4 = (float4*)&s1T[t*16];
    s4[0] = make_float4(z[0],  z[1],  z[2],  z[3]);
    s4[1] = make_float4(z[4],  z[5],  z[6],  z[7]);
    s4[2] = make_float4(z[8],  z[9],  z[10], z[11]);
    s4[3] = make_float4(z[12], z[13], z[14], z[15]);
  }
  __syncthreads();
  // fc2: 2 threads per column (l split in halves of 256)
  int c = t & 255, half = t >> 8;
  float z2[BG];
  #pragma unroll
  for (int r = 0; r < BG; r++) z2[r] = 0.f;
  int l0 = half*256;
  #pragma unroll 2
  for (int l = l0; l < l0 + 256; l++){
    float w = wf2[l*256 + c];
    const float4* e4 = (const float4*)&s1T[l*16];
    float4 e0 = e4[0], e1 = e4[1], e2 = e4[2], e3 = e4[3];
    z2[0]  += e0.x*w; z2[1]  += e0.y*w; z2[2]  += e0.z*w; z2[3]  += e0.w*w;
    z2[4]  += e1.x*w; z2[5]  += e1.y*w; z2[6]  += e1.z*w; z2[7]  += e1.w*w;
    z2[8]  += e2.x*w; z2[9]  += e2.y*w; z2[10] += e2.z*w; z2[11] += e2.w*w;
    z2[12] += e3.x*w; z2[13] += e3.y*w; z2[14] += e3.z*w; z2[15] += e3.w*w;
  }
  if (half == 1){
    float4* p4 = (float4*)&zp[c*16];
    p4[0] = make_float4(z2[0],  z2[1],  z2[2],  z2[3]);
    p4[1] = make_float4(z2[4],  z2[5],  z2[6],  z2[7]);
    p4[2] = make_float4(z2[8],  z2[9],  z2[10], z2[11]);
    p4[3] = make_float4(z2[12], z2[13], z2[14], z2[15]);
  }
  __syncthreads();
  float* s2T = s1T;                          // s1T dead; reuse as s2T[256][16]
  if (half == 0){
    const float4* p4 = (const float4*)&zp[c*16];
    float4 q0 = p4[0], q1 = p4[1], q2 = p4[2], q3 = p4[3];
    z2[0]  += q0.x; z2[1]  += q0.y; z2[2]  += q0.z; z2[3]  += q0.w;
    z2[4]  += q1.x; z2[5]  += q1.y; z2[6]  += q1.z; z2[7]  += q1.w;
    z2[8]  += q2.x; z2[9]  += q2.y; z2[10] += q2.z; z2[11] += q2.w;
    z2[12] += q3.x; z2[13] += q3.y; z2[14] += q3.z; z2[15] += q3.w;
    float bb = bf2[c];
    float s = 0.f, qq = 0.f;
    #pragma unroll
    for (int r = 0; r < BG; r++){ float zr = z2[r] + bb; s += zr; qq += zr*zr; }
    float mean = s*(1.0f/BG), var = qq*(1.0f/BG) - mean*mean;
    float inv = rsqrtf(var + BNEPS);
    float gg = gf2[c], b2 = bef2[c];
    #pragma unroll
    for (int r = 0; r < BG; r++) z2[r] = fmaxf(gg*(z2[r] + bb - mean)*inv + b2, 0.f);
    float4* o4 = (float4*)&s2T[c*16];
    o4[0] = make_float4(z2[0],  z2[1],  z2[2],  z2[3]);
    o4[1] = make_float4(z2[4],  z2[5],  z2[6],  z2[7]);
    o4[2] = make_float4(z2[8],  z2[9],  z2[10], z2[11]);
    o4[3] = make_float4(z2[12], z2[13], z2[14], z2[15]);
  }
  __syncthreads();
  float* sl = zp;                            // zp dead; reuse for logits [16][16]
  if (t < BG*NCL){
    int r = t / NCL, cc = t - r*NCL;
    float sacc = bf3[cc];
    for (int k = 0; k < 256; k++) sacc += s2T[k*16 + r] * wf3[k*NCL + cc];
    sl[r*16 + cc] = sacc;
  }
  __syncthreads();
  if (t < BG){
    float m = -1e30f;
    for (int cc = 0; cc < NCL; cc++) m = fmaxf(m, sl[t*16 + cc]);
    float se = 0.f;
    for (int cc = 0; cc < NCL; cc++) se += expf(sl[t*16 + cc] - m);
    float lg = logf(se) + m;
    for (int cc = 0; cc < NCL; cc++) out[t*NCL + cc] = sl[t*16 + cc] - lg;
  }
}

extern "C" void kernel_launch(void* const* d_in, const int* in_sizes, int n_in,
                              void* d_out, int out_size, void* d_ws, size_t ws_size,
                              hipStream_t stream){
  const float* x    = (const float*)d_in[0];
  const float* ea   = (const float*)d_in[1];
  const float* we   = (const float*)d_in[2];
  const float* bedg = (const float*)d_in[3];
  const float* w1   = (const float*)d_in[4];  const float* b1  = (const float*)d_in[5];
  const float* g1   = (const float*)d_in[6];  const float* be1 = (const float*)d_in[7];
  const float* w2   = (const float*)d_in[8];  const float* b2  = (const float*)d_in[9];
  const float* g2   = (const float*)d_in[10]; const float* be2 = (const float*)d_in[11];
  const float* w3   = (const float*)d_in[12]; const float* b3  = (const float*)d_in[13];
  const float* g3   = (const float*)d_in[14]; const float* be3 = (const float*)d_in[15];
  const float* wf1  = (const float*)d_in[16]; const float* bf1 = (const float*)d_in[17];
  const float* gf1  = (const float*)d_in[18]; const float* bef1= (const float*)d_in[19];
  const float* wf2  = (const float*)d_in[20]; const float* bf2 = (const float*)d_in[21];
  const float* gf2  = (const float*)d_in[22]; const float* bef2= (const float*)d_in[23];
  const float* wf3  = (const float*)d_in[24]; const float* bf3 = (const float*)d_in[25];
  const void* ei    = d_in[26];
  const void* batch = d_in[27];
  float* out = (float*)d_out;

  u64* wq = (u64*)d_ws;
  u64* deg_cnt = wq; wq += NN;
  u64* csr_p   = wq; wq += NELL;
  float* ws = (float*)wq;
  float* P1    = ws; ws += NN*FH1;
  float* P2    = ws; ws += NN*FH2;
  float* P3    = ws; ws += NN*FH2;
  float* csp1  = ws; ws += NBANK*128;
  float* csp2  = ws; ws += NBANK*128;
  float* csp3  = ws; ws += NBANK*128;
  float* dis   = ws; ws += NN;
  float* embf  = ws; ws += BG*64;
  int* flags   = (int*)ws;                   // [0]=ei64 [1]=batch64

  k_pre<<<48, 256, 0, stream>>>(deg_cnt, csp1, csp2, csp3, embf, ei, batch, flags);
  k_edge<<<cdiv(EE,256), 256, 0, stream>>>(ea, we, bedg, ei, flags, deg_cnt, csr_p);
  k_dis<<<48, 256, 0, stream>>>(deg_cnt, dis);

  // layer 1: x(15) -> P1(32)
  k_layer<FIN,16,FH1,0><<<NN/16, 256, 0, stream>>>(x, nullptr, nullptr, nullptr,
      w1, b1, deg_cnt, csr_p, dis, P1, csp1);
  // layer 2: BN1(P1)(32) -> P2(64)   (BN coeffs from csp1 inline)
  k_layer<FH1,32,FH2,1><<<NN/8, 256, 0, stream>>>(P1, csp1, g1, be1,
      w2, b2, deg_cnt, csr_p, dis, P2, csp2);
  // layer 3: BN2(P2)(64) -> P3(64)   (BN coeffs from csp2 inline)
  k_layer<FH2,64,FH2,1><<<NN/4, 256, 0, stream>>>(P2, csp2, g2, be2,
      w3, b3, deg_cnt, csr_p, dis, P3, csp3);

  k_pool<<<256, 256, 0, stream>>>(P3, csp3, g3, be3, batch, flags, embf);
  k_head<<<1, 512, 0, stream>>>(embf, wf1, bf1, gf1, bef1,
      wf2, bf2, gf2, bef2, wf3, bf3, out);
}

// Round 4
// 233.856 us; speedup vs baseline: 1.1714x; 1.1714x over previous
//
#include <hip/hip_runtime.h>
#include <hip/hip_bf16.h>

#define NN   12288
#define EE   393216
#define WELL 128                // ELL slots per row (pow2; max degree ~64)
#define NELL (NN*WELL)
#define BG   16
#define FIN  15
#define FH1  32
#define FH2  64
#define NCL  11
#define BNEPS 1e-5f
#define NBANK 32

typedef unsigned long long u64;
static inline int cdiv(long a, long b){ return (int)((a + b - 1) / b); }

__device__ __forceinline__ int getIdx(const void* p, long i, int is64){
  return is64 ? (int)((const long long*)p)[i] : ((const int*)p)[i];
}

// ---- pre: zero deg_cnt + csp banks + embf; detect int width ----
__global__ void k_pre(u64* deg_cnt, float* csp1, float* csp2, float* csp3,
                      float* embf, const void* ei, const void* batch, int* flags){
  int g = blockIdx.x*256 + threadIdx.x;
  if (g < NN) deg_cnt[g] = 0ull;
  if (g < NBANK*128){ csp1[g] = 0.f; csp2[g] = 0.f; csp3[g] = 0.f; }
  if (g < BG*64) embf[g] = 0.f;          // pool accumulates via atomicMax, vals >= 0
  if (blockIdx.x == 0 && threadIdx.x < 64){
    const int* a = (const int*)ei;
    unsigned long long m0 = __ballot(a[2*threadIdx.x + 1] == 0);
    const int* b = (const int*)batch;
    int j = 96*threadIdx.x;
    unsigned long long m1 = __ballot(b[2*j + 1] == 0);
    if (threadIdx.x == 0){
      flags[0] = (m0 == ~0ull) ? 1 : 0;
      flags[1] = (m1 == ~0ull) ? 1 : 0;
    }
  }
}

// ---- edge pass: ONE u64 atomic per edge; returned count = ELL slot ----
__global__ void k_edge(const float* ea, const float* we, const float* bedg,
                       const void* ei, const int* flags, u64* deg_cnt, u64* csr_p){
  int e = blockIdx.x*256 + threadIdx.x;
  if (e >= EE) return;
  int is64 = flags[0];
  float2 eav = ((const float2*)ea)[e];
  float z = eav.x*we[0] + eav.y*we[1] + bedg[0];
  float w = 1.0f/(1.0f + expf(-z));
  int r = getIdx(ei, e, is64);
  int c = getIdx(ei, (long)EE + e, is64);
  u64 add = (1ull << 32) | (u64)__float2uint_rn(w * 1048576.0f);
  u64 old = atomicAdd(&deg_cnt[r], add);
  int slot = (int)(old >> 32);
  if (slot < WELL)
    csr_p[((long)r << 7) + slot] = (u64)(unsigned)c | ((u64)__float_as_uint(w) << 32);
}

// ---- dis LUT: rsqrt(deg) per node (replaces the 1.57M-thread k_fix sweep) ----
__global__ void k_dis(const u64* __restrict__ deg_cnt, float* __restrict__ dis){
  int g = blockIdx.x*256 + threadIdx.x;
  if (g < NN){
    unsigned lo = (unsigned)(deg_cnt[g] & 0xffffffffull);
    dis[g] = rsqrtf(1.0f + (float)lo * (1.0f/1048576.0f));
  }
}

// ---- fused GCN layer, one tile per block, ELL chunks of 8 + prefetch.
// Column normalization via dis[] LUT (k_fix eliminated).
// BN coefficients computed per-block from csp banks (k_stat eliminated).
template<int F, int FP, int FO, int APPLY_BN>
__global__ void __launch_bounds__(256) k_layer(
    const float* __restrict__ Hin,
    const float* __restrict__ cspin, const float* __restrict__ gam,
    const float* __restrict__ bet,
    const float* __restrict__ W, const float* __restrict__ bias,
    const u64* __restrict__ deg_cnt, const u64* __restrict__ csr_p,
    const float* __restrict__ dis,
    float* __restrict__ Pout, float* __restrict__ csout){
  const int R = 256/FP;
  __shared__ float At[R][FP];
  __shared__ float lcs[FO], lcq[FO];
  __shared__ float lsc[64], lsh[64];
  if (threadIdx.x < FO){ lcs[threadIdx.x] = 0.f; lcq[threadIdx.x] = 0.f; }
  if (APPLY_BN && threadIdx.x < F){
    float s = 0.f, q = 0.f;
    #pragma unroll
    for (int b = 0; b < NBANK; b++){
      s += cspin[b*128 + threadIdx.x];
      q += cspin[b*128 + 64 + threadIdx.x];
    }
    float mu  = s*(1.0f/NN);
    float var = q*(1.0f/NN) - mu*mu;
    float sc = gam[threadIdx.x]*rsqrtf(var + BNEPS);
    lsc[threadIdx.x] = sc;
    lsh[threadIdx.x] = bet[threadIdx.x] - mu*sc;
  }
  __syncthreads();
  int f = threadIdx.x % FP, lr = threadIdx.x / FP;
  float sc = 1.f, sh = 0.f;
  if (APPLY_BN && f < F){ sc = lsc[f]; sh = lsh[f]; }
  int row = blockIdx.x*R + lr;
  if (f < F){
    float d = dis[row];
    int n = (int)(deg_cnt[row] >> 32);
    n = n < WELL ? n : WELL;
    float v0 = Hin[row*F + f];
    if (APPLY_BN) v0 = fmaxf(v0*sc + sh, 0.f);
    float acc = d * v0;                       // self loop
    int nch = (n + 7) >> 3;
    const uint4* pb = (const uint4*)(csr_p + ((long)row << 7));
    if (nch > 0){
      uint4 a0 = pb[0], a1 = pb[1], a2 = pb[2], a3 = pb[3];
      for (int ch = 0; ch < nch; ch++){
        uint4 b0, b1, b2, b3;
        bool more = (ch + 1 < nch);
        if (more){ b0 = pb[4*ch+4]; b1 = pb[4*ch+5]; b2 = pb[4*ch+6]; b3 = pb[4*ch+7]; }
        int base = ch*8;
        if (base + 8 > n){                    // mask garbage tail slots
          if (base+0 >= n){ a0.x = 0u; a0.y = 0u; }
          if (base+1 >= n){ a0.z = 0u; a0.w = 0u; }
          if (base+2 >= n){ a1.x = 0u; a1.y = 0u; }
          if (base+3 >= n){ a1.z = 0u; a1.w = 0u; }
          if (base+4 >= n){ a2.x = 0u; a2.y = 0u; }
          if (base+5 >= n){ a2.z = 0u; a2.w = 0u; }
          if (base+6 >= n){ a3.x = 0u; a3.y = 0u; }
          if (base+7 >= n){ a3.z = 0u; a3.w = 0u; }
        }
        float w0 = __uint_as_float(a0.y) * dis[(int)a0.x];
        float w1 = __uint_as_float(a0.w) * dis[(int)a0.z];
        float w2 = __uint_as_float(a1.y) * dis[(int)a1.x];
        float w3 = __uint_as_float(a1.w) * dis[(int)a1.z];
        float w4 = __uint_as_float(a2.y) * dis[(int)a2.x];
        float w5 = __uint_as_float(a2.w) * dis[(int)a2.z];
        float w6 = __uint_as_float(a3.y) * dis[(int)a3.x];
        float w7 = __uint_as_float(a3.w) * dis[(int)a3.z];
        float h0 = Hin[(int)a0.x*F + f];
        float h1 = Hin[(int)a0.z*F + f];
        float h2 = Hin[(int)a1.x*F + f];
        float h3 = Hin[(int)a1.z*F + f];
        float h4 = Hin[(int)a2.x*F + f];
        float h5 = Hin[(int)a2.z*F + f];
        float h6 = Hin[(int)a3.x*F + f];
        float h7 = Hin[(int)a3.z*F + f];
        if (APPLY_BN){
          h0 = fmaxf(h0*sc + sh, 0.f); h1 = fmaxf(h1*sc + sh, 0.f);
          h2 = fmaxf(h2*sc + sh, 0.f); h3 = fmaxf(h3*sc + sh, 0.f);
          h4 = fmaxf(h4*sc + sh, 0.f); h5 = fmaxf(h5*sc + sh, 0.f);
          h6 = fmaxf(h6*sc + sh, 0.f); h7 = fmaxf(h7*sc + sh, 0.f);
        }
        acc += w0*h0 + w1*h1 + w2*h2 + w3*h3
             + w4*h4 + w5*h5 + w6*h6 + w7*h7;
        if (more){ a0 = b0; a1 = b1; a2 = b2; a3 = b3; }
      }
    }
    At[lr][f] = d * acc;
  }
  __syncthreads();
  const int fo = threadIdx.x % FO;     // 256 % FO == 0
  float bb = bias[fo];
  for (int o = threadIdx.x; o < R*FO; o += 256){
    int l = o / FO;
    float s = bb;
    #pragma unroll
    for (int fi = 0; fi < F; fi++) s += At[l][fi] * W[fi*FO + fo];
    Pout[(blockIdx.x*R + l)*FO + fo] = s;
    atomicAdd(&lcs[fo], s);
    atomicAdd(&lcq[fo], s*s);
  }
  __syncthreads();
  if (threadIdx.x < FO){
    int bank = blockIdx.x & (NBANK-1);
    atomicAdd(&csout[bank*128 + threadIdx.x],      lcs[threadIdx.x]);
    atomicAdd(&csout[bank*128 + 64 + threadIdx.x], lcq[threadIdx.x]);
  }
}

// ---- pool: 16 chunks per graph (256 blocks); inline BN3 prep; atomicMax merge.
// Pooled values >= 0 (relu): int-compare on float bits is monotone; zero-init ok.
__global__ void k_pool(const float* P3, const float* csp, const float* gam,
                       const float* bet, const void* batch, const int* flags,
                       float* embf){
  __shared__ float lsc[64], lsh[64];
  if (threadIdx.x < 64){
    float s = 0.f, q = 0.f;
    #pragma unroll
    for (int b = 0; b < NBANK; b++){
      s += csp[b*128 + threadIdx.x];
      q += csp[b*128 + 64 + threadIdx.x];
    }
    float mu  = s*(1.0f/NN);
    float var = q*(1.0f/NN) - mu*mu;
    float sc = gam[threadIdx.x]*rsqrtf(var + BNEPS);
    lsc[threadIdx.x] = sc;
    lsh[threadIdx.x] = bet[threadIdx.x] - mu*sc;
  }
  __syncthreads();
  int is64 = flags[1];
  int b = blockIdx.x & 15, chunk = blockIdx.x >> 4;
  int lo = 0, hi = NN;
  while (lo < hi){ int m = (lo+hi)>>1; if (getIdx(batch, m, is64) < b) lo = m+1; else hi = m; }
  int start = lo;
  lo = start; hi = NN;
  while (lo < hi){ int m = (lo+hi)>>1; if (getIdx(batch, m, is64) < b+1) lo = m+1; else hi = m; }
  int end = lo;
  int f = threadIdx.x & 63, grp = threadIdx.x >> 6;
  float sc = lsc[f], sh = lsh[f];
  float m = 0.0f;
  for (int i = start + chunk*4 + grp; i < end; i += 64)
    m = fmaxf(m, P3[(long)i*FH2 + f]*sc + sh);
  __shared__ float shm[4][64];
  shm[grp][f] = m;
  __syncthreads();
  if (grp == 0){
    float v = fmaxf(fmaxf(shm[0][f], shm[1][f]), fmaxf(shm[2][f], shm[3][f]));
    atomicMax((int*)&embf[b*64 + f], __float_as_int(v));
  }
}

// ---- head fc1 + BN + relu: wave per column; block 0 also copies emb -> out ----
__global__ void __launch_bounds__(256) k_fcA(const float* embf, const float* wf1,
    const float* bf1, const float* gf1, const float* bef1, float* s1g, float* out){
  if (blockIdx.x == 0){
    #pragma unroll
    for (int i = 0; i < 4; i++)
      out[BG*NCL + i*256 + threadIdx.x] = embf[i*256 + threadIdx.x];
  }
  int c = blockIdx.x*4 + (threadIdx.x >> 6);
  int l = threadIdx.x & 63;
  float wcol = wf1[l*512 + c];
  float z[BG];
  #pragma unroll
  for (int r = 0; r < BG; r++){
    float v = embf[r*64 + l] * wcol;
    #pragma unroll
    for (int off = 32; off > 0; off >>= 1) v += __shfl_down(v, off);
    z[r] = v;                 // valid on lane 0
  }
  if (l == 0){
    float bb = bf1[c];
    float s = 0.f, q = 0.f;
    #pragma unroll
    for (int r = 0; r < BG; r++){ float zr = z[r] + bb; s += zr; q += zr*zr; }
    float mean = s*(1.f/BG), var = q*(1.f/BG) - mean*mean;
    float inv = rsqrtf(var + BNEPS);
    float gg = gf1[c], b2 = bef1[c];
    #pragma unroll
    for (int r = 0; r < BG; r++)
      s1g[r*512 + c] = fmaxf(gg*(z[r] + bb - mean)*inv + b2, 0.f);
  }
}

// ---- head fc2 + BN + relu: wave per column ----
__global__ void __launch_bounds__(256) k_fcB(const float* s1g, const float* wf2,
    const float* bf2, const float* gf2, const float* bef2, float* s2g){
  int c = blockIdx.x*4 + (threadIdx.x >> 6);
  int l = threadIdx.x & 63;
  float wreg[8];
  #pragma unroll
  for (int j = 0; j < 8; j++) wreg[j] = wf2[(l + 64*j)*256 + c];
  float z[BG];
  #pragma unroll
  for (int r = 0; r < BG; r++){
    float v = 0.f;
    #pragma unroll
    for (int j = 0; j < 8; j++) v += s1g[r*512 + l + 64*j] * wreg[j];
    #pragma unroll
    for (int off = 32; off > 0; off >>= 1) v += __shfl_down(v, off);
    z[r] = v;
  }
  if (l == 0){
    float bb = bf2[c];
    float s = 0.f, q = 0.f;
    #pragma unroll
    for (int r = 0; r < BG; r++){ float zr = z[r] + bb; s += zr; q += zr*zr; }
    float mean = s*(1.f/BG), var = q*(1.f/BG) - mean*mean;
    float inv = rsqrtf(var + BNEPS);
    float gg = gf2[c], b2 = bef2[c];
    #pragma unroll
    for (int r = 0; r < BG; r++)
      s2g[r*256 + c] = fmaxf(gg*(z[r] + bb - mean)*inv + b2, 0.f);
  }
}

// ---- head fc3 + log_softmax ----
__global__ void k_fc3(const float* s2g, const float* wf3, const float* bf3, float* out){
  __shared__ float s2[BG*256];
  __shared__ float sl[BG*NCL];
  int t = threadIdx.x;
  for (int i = t; i < BG*256; i += 256) s2[i] = s2g[i];
  __syncthreads();
  if (t < BG*NCL){
    int r = t / NCL, c = t - r*NCL;
    float s = bf3[c];
    for (int k = 0; k < 256; k++) s += s2[r*256 + k]*wf3[k*NCL + c];
    sl[t] = s;
  }
  __syncthreads();
  if (t < BG){
    float m = -1e30f;
    for (int c = 0; c < NCL; c++) m = fmaxf(m, sl[t*NCL + c]);
    float s = 0.f;
    for (int c = 0; c < NCL; c++) s += expf(sl[t*NCL + c] - m);
    float lg = logf(s) + m;
    for (int c = 0; c < NCL; c++) out[t*NCL + c] = sl[t*NCL + c] - lg;
  }
}

extern "C" void kernel_launch(void* const* d_in, const int* in_sizes, int n_in,
                              void* d_out, int out_size, void* d_ws, size_t ws_size,
                              hipStream_t stream){
  const float* x    = (const float*)d_in[0];
  const float* ea   = (const float*)d_in[1];
  const float* we   = (const float*)d_in[2];
  const float* bedg = (const float*)d_in[3];
  const float* w1   = (const float*)d_in[4];  const float* b1  = (const float*)d_in[5];
  const float* g1   = (const float*)d_in[6];  const float* be1 = (const float*)d_in[7];
  const float* w2   = (const float*)d_in[8];  const float* b2  = (const float*)d_in[9];
  const float* g2   = (const float*)d_in[10]; const float* be2 = (const float*)d_in[11];
  const float* w3   = (const float*)d_in[12]; const float* b3  = (const float*)d_in[13];
  const float* g3   = (const float*)d_in[14]; const float* be3 = (const float*)d_in[15];
  const float* wf1  = (const float*)d_in[16]; const float* bf1 = (const float*)d_in[17];
  const float* gf1  = (const float*)d_in[18]; const float* bef1= (const float*)d_in[19];
  const float* wf2  = (const float*)d_in[20]; const float* bf2 = (const float*)d_in[21];
  const float* gf2  = (const float*)d_in[22]; const float* bef2= (const float*)d_in[23];
  const float* wf3  = (const float*)d_in[24]; const float* bf3 = (const float*)d_in[25];
  const void* ei    = d_in[26];
  const void* batch = d_in[27];
  float* out = (float*)d_out;

  u64* wq = (u64*)d_ws;
  u64* deg_cnt = wq; wq += NN;
  u64* csr_p   = wq; wq += NELL;
  float* ws = (float*)wq;
  float* P1    = ws; ws += NN*FH1;
  float* P2    = ws; ws += NN*FH2;
  float* P3    = ws; ws += NN*FH2;
  float* csp1  = ws; ws += NBANK*128;
  float* csp2  = ws; ws += NBANK*128;
  float* csp3  = ws; ws += NBANK*128;
  float* dis   = ws; ws += NN;
  float* embf  = ws; ws += BG*64;
  float* s1g   = ws; ws += BG*512;
  float* s2g   = ws; ws += BG*256;
  int* flags   = (int*)ws;                   // [0]=ei64 [1]=batch64

  k_pre<<<48, 256, 0, stream>>>(deg_cnt, csp1, csp2, csp3, embf, ei, batch, flags);
  k_edge<<<cdiv(EE,256), 256, 0, stream>>>(ea, we, bedg, ei, flags, deg_cnt, csr_p);
  k_dis<<<48, 256, 0, stream>>>(deg_cnt, dis);

  // layer 1: x(15) -> P1(32)
  k_layer<FIN,16,FH1,0><<<NN/16, 256, 0, stream>>>(x, nullptr, nullptr, nullptr,
      w1, b1, deg_cnt, csr_p, dis, P1, csp1);
  // layer 2: BN1(P1)(32) -> P2(64)   (BN coeffs from csp1 inline)
  k_layer<FH1,32,FH2,1><<<NN/8, 256, 0, stream>>>(P1, csp1, g1, be1,
      w2, b2, deg_cnt, csr_p, dis, P2, csp2);
  // layer 3: BN2(P2)(64) -> P3(64)   (BN coeffs from csp2 inline)
  k_layer<FH2,64,FH2,1><<<NN/4, 256, 0, stream>>>(P2, csp2, g2, be2,
      w3, b3, deg_cnt, csr_p, dis, P3, csp3);

  k_pool<<<256, 256, 0, stream>>>(P3, csp3, g3, be3, batch, flags, embf);
  k_fcA<<<128, 256, 0, stream>>>(embf, wf1, bf1, gf1, bef1, s1g, out);
  k_fcB<<<64, 256, 0, stream>>>(s1g, wf2, bf2, gf2, bef2, s2g);
  k_fc3<<<1, 256, 0, stream>>>(s2g, wf3, bf3, out);
}